// Round 18
// baseline (298.827 us; speedup 1.0000x reference)
//
#include <hip/hip_runtime.h>

typedef unsigned short u16;
typedef u16 u16x4 __attribute__((ext_vector_type(4)));
typedef u16 u16x8 __attribute__((ext_vector_type(8)));
typedef __bf16 bf16;
typedef bf16 bf16x8 __attribute__((ext_vector_type(8)));
typedef float f32x4 __attribute__((ext_vector_type(4)));

__device__ __forceinline__ float bf2f(u16 v) {
  union { unsigned u; float f; } x; x.u = ((unsigned)v) << 16; return x.f;
}
__device__ __forceinline__ u16 f2bf(float f) {
  union { float f; unsigned u; } x; x.f = f;
  unsigned u = x.u;
  u += 0x7fffu + ((u >> 16) & 1u);   // RNE
  return (u16)(u >> 16);
}
// hw packed f32->bf16 (RNE), 2 values / instr (no builtin on gfx950, m240)
__device__ __forceinline__ unsigned cvt2bf(float lo, float hi) {
  unsigned r;
  asm("v_cvt_pk_bf16_f32 %0, %1, %2" : "=v"(r) : "v"(lo), "v"(hi));
  return r;
}

// lgkm-only barrier: LDS drained, global loads stay in flight
__device__ __forceinline__ void bar_lgkm() {
  asm volatile("s_waitcnt lgkmcnt(0)" ::: "memory");
  __builtin_amdgcn_s_barrier();
}

// async global->LDS, 16B per lane; LDS base wave-uniform, global source per-lane (m173)
#define GLDS16(g, l) __builtin_amdgcn_global_load_lds( \
    (const __attribute__((address_space(1))) unsigned int*)(const void*)(g), \
    (__attribute__((address_space(3))) unsigned int*)(void*)(l), 16, 0, 0)

// ---------------- prep (tiny): 4 weight transposes + bias cvts ----------------
// grid 588: [0,576) transpose4; [576,588) bias (3072). Query cvt DELETED (gds reads fp32).
__global__ __launch_bounds__(256) void prep_k(
    const float* __restrict__ Wq, const float* __restrict__ Wk,
    const float* __restrict__ Wv, const float* __restrict__ Wout,
    const float* __restrict__ b0, const float* __restrict__ b1,
    const float* __restrict__ b2, const float* __restrict__ b3,
    u16* __restrict__ WT, u16* __restrict__ dstB)
{
  __shared__ u16 T[64][72];
  const int blk = blockIdx.x;
  const int t = threadIdx.x;
  if (blk < 576) {
    const int bz = blk / 144, rr = blk % 144;
    const int r0 = (rr / 12) * 64, c0 = (rr % 12) * 64;
    const float* W = (bz == 0) ? Wq : (bz == 1) ? Wk : (bz == 2) ? Wv : Wout;
    u16* O = WT + (size_t)bz * 768 * 768;
    #pragma unroll
    for (int p = 0; p < 2; ++p) {
      int v = t + p * 256;
      int r = v / 8, c = (v % 8) * 8;
      f32x4 x0 = *(const f32x4*)&W[(size_t)(r0 + r) * 768 + c0 + c];
      f32x4 x1 = *(const f32x4*)&W[(size_t)(r0 + r) * 768 + c0 + c + 4];
      #pragma unroll
      for (int i = 0; i < 4; ++i) { T[r][c + i] = f2bf(x0[i]); T[r][c + 4 + i] = f2bf(x1[i]); }
    }
    __syncthreads();
    #pragma unroll
    for (int p = 0; p < 2; ++p) {
      int v = t + p * 256;
      int r = v / 8, c = (v % 8) * 8;
      u16x8 tv;
      #pragma unroll
      for (int i = 0; i < 8; ++i) tv[i] = T[c + i][r];
      *(u16x8*)&O[(size_t)(c0 + r) * 768 + r0 + c] = tv;
    }
  } else {
    const int i = (blk - 576) * 256 + t;   // 3072
    if (i < 3072) {
      int s = i / 768, si = i % 768;
      const float* src = (s == 0) ? b0 : (s == 1) ? b1 : (s == 2) ? b2 : b3;
      dstB[i] = f2bf(src[si]);
    }
  }
}

// ---------------- merged phi_q GEMM (fp32 A direct) + downsample ----------------
// Even blk: gemmqf (R6-proven math): phi_q = elu(query@WqT+bq)+1, A staged fp32 via
// GLDS (16B chunks, ch^(r&15) swizzle), cvt_pk at fragment read. Its barrier drains
// are absorbed by co-resident ds blocks (R17-proven mechanism).
// Odd blk: ds v8 (R14-proven). Deletes q_bf: -75MB traffic, prep -18us.
__global__ __launch_bounds__(256) void gds_k(
    const float* __restrict__ Aq,     // query fp32 [16384][768]
    const u16* __restrict__ Bt,       // WqT
    u16* __restrict__ C,              // phi_q
    const u16* __restrict__ bias,     // bq
    const float* __restrict__ W_kds, const float* __restrict__ W_vds,
    const float* __restrict__ key, const float* __restrict__ value,
    u16* __restrict__ key_ds)
{
  __shared__ char sm[51200];
  const int t = threadIdx.x, wave = t >> 6, lane = t & 63;
  const int lrow = lane & 15, quad = lane >> 4;
  const int sub = blockIdx.x >> 1;

  if ((blockIdx.x & 1) == 0) {
    // ---- gemmqf branch: fp32 A, BK=64 ----
    float* As = (float*)sm;           // 32KB fp32 [128][64], chunk-swizzled ch^(r&15)
    u16* Bs = (u16*)(sm + 32768);     // 16KB, swizzled ch^(r&7)
    const int wg = (sub & 7) * 96 + (sub >> 3);
    const int mt = (wg / 6) * 128, nt = (wg % 6) * 128;
    const int wm = (wave >> 1) * 64, wn = (wave & 1) * 64;
    f32x4 acc[4][4] = {};

    for (int k0 = 0; k0 < 768; k0 += 64) {
      __syncthreads();
      #pragma unroll
      for (int p = 0; p < 8; ++p) {   // A: 2048 slots x 16B (4 f32)
        const int slot = wave * 512 + p * 64 + lane;
        const int r = slot >> 4, ch = slot & 15;
        const int chs = ch ^ (r & 15);
        GLDS16(&Aq[(size_t)(mt + r) * 768 + k0 + chs * 4],
               (char*)As + (wave * 512 + p * 64) * 16);
      }
      #pragma unroll
      for (int p = 0; p < 4; ++p) {   // B: 1024 slots x 16B
        const int slot = wave * 256 + p * 64 + lane;
        const int r = slot >> 3, ch = slot & 7;
        const int chs = ch ^ (r & 7);
        GLDS16(&Bt[(size_t)(nt + r) * 768 + k0 + chs * 8],
               (char*)Bs + (wave * 256 + p * 64) * 16);
      }
      __syncthreads();
      #pragma unroll
      for (int c = 0; c < 2; ++c) {
        bf16x8 av[4], bv[4];
        #pragma unroll
        for (int i = 0; i < 4; ++i) {
          const int row = wm + i * 16 + lrow;
          const int g0 = c * 8 + 2 * quad;
          f32x4 a0 = *(const f32x4*)&As[row * 64 + ((g0 ^ (row & 15)) * 4)];
          f32x4 a1 = *(const f32x4*)&As[row * 64 + (((g0 + 1) ^ (row & 15)) * 4)];
          union { unsigned w[4]; bf16x8 v; } cv;
          cv.w[0] = cvt2bf(a0[0], a0[1]); cv.w[1] = cvt2bf(a0[2], a0[3]);
          cv.w[2] = cvt2bf(a1[0], a1[1]); cv.w[3] = cvt2bf(a1[2], a1[3]);
          av[i] = cv.v;
        }
        #pragma unroll
        for (int j = 0; j < 4; ++j) {
          const int row = wn + j * 16 + lrow;
          bv[j] = *(const bf16x8*)&Bs[row * 64 + (((c * 4 + quad) ^ (row & 7)) * 8)];
        }
        #pragma unroll
        for (int i = 0; i < 4; ++i)
          #pragma unroll
          for (int j = 0; j < 4; ++j)
            acc[i][j] = __builtin_amdgcn_mfma_f32_16x16x32_bf16(av[i], bv[j], acc[i][j], 0, 0, 0);
      }
    }
    #pragma unroll
    for (int i = 0; i < 4; ++i)
      #pragma unroll
      for (int j = 0; j < 4; ++j) {
        const int col = nt + wn + j * 16 + lrow;
        const float badd = bf2f(bias[col]);
        #pragma unroll
        for (int r = 0; r < 4; ++r) {
          const int row = mt + wm + i * 16 + quad * 4 + r;
          float v = acc[i][j][r] + badd;
          v = v > 0.0f ? v + 1.0f : __expf(v);
          C[(size_t)row * 768 + col] = f2bf(v);
        }
      }
    return;
  }

  // ---- ds v8 branch ----
  const int id = sub;
  const int nt = (id % 12) * 64;
  const int yb = id / 12;
  const int pair = yb >> 5, b = yb & 31;
  const float* src = (pair ? value : key) + (size_t)b * 512 * 768;
  const float* W32 = pair ? W_vds : W_kds;     // fp32 [64][512], L2-hot
  u16* dst = key_ds + (size_t)pair * 1572864 + (size_t)b * 49152;
  const int wm = wave * 16;
  const int k4 = t >> 4, n4 = t & 15;

  bf16x8 wreg[16];
  #pragma unroll
  for (int c = 0; c < 16; ++c) {
    const float* wr = &W32[(size_t)(wm + lrow) * 512 + c * 32 + quad * 8];
    f32x4 w0 = *(const f32x4*)wr;
    f32x4 w1 = *(const f32x4*)(wr + 4);
    union { unsigned u[4]; bf16x8 v; } cv;
    cv.u[0] = cvt2bf(w0[0], w0[1]); cv.u[1] = cvt2bf(w0[2], w0[3]);
    cv.u[2] = cvt2bf(w1[0], w1[1]); cv.u[3] = cvt2bf(w1[2], w1[3]);
    wreg[c] = cv.v;
  }

  auto Sg = [&](int bufi) -> float* { return (float*)(sm + bufi * 16384); };
  auto Kb = [&](int bufi) -> u16*   { return (u16*)(sm + 32768 + bufi * 9216); };

  auto stage = [&](int bufi, int kb) {
    #pragma unroll
    for (int p = 0; p < 4; ++p) {
      const int g = wave * 4 + p;
      const int row = kb + g * 4 + (lane >> 4);
      const int ch = (lane & 15) ^ (g & 15);
      GLDS16(&src[(size_t)row * 768 + nt + ch * 4], (char*)Sg(bufi) + g * 1024);
    }
  };
  auto transp = [&](int bufi) {
    float* S = Sg(bufi);
    u16* K = Kb(bufi);
    f32x4 r[4];
    #pragma unroll
    for (int i = 0; i < 4; ++i) {
      const int k = k4 * 4 + i;
      r[i] = *(const f32x4*)&S[k * 64 + ((n4 ^ (k4 & 15)) & 15) * 4];
    }
    #pragma unroll
    for (int nn = 0; nn < 4; ++nn) {
      unsigned* p2 = (unsigned*)&K[(n4 * 4 + nn) * 72 + k4 * 4];
      p2[0] = cvt2bf(r[0][nn], r[1][nn]);
      p2[1] = cvt2bf(r[2][nn], r[3][nn]);
    }
  };

  f32x4 acc[4] = {};
  stage(0, 0);
  __syncthreads();
  stage(1, 64);
  transp(0);
  bar_lgkm();
  int cur = 0;
  #pragma unroll
  for (int cc = 0; cc < 8; ++cc) {
    #pragma unroll
    for (int kc = 0; kc < 2; ++kc) {
      bf16x8 bv[4];
      #pragma unroll
      for (int j = 0; j < 4; ++j) {
        const int n = j * 16 + lrow;
        bv[j] = *(const bf16x8*)&Kb(cur)[n * 72 + kc * 32 + quad * 8];
      }
      #pragma unroll
      for (int j = 0; j < 4; ++j)
        acc[j] = __builtin_amdgcn_mfma_f32_16x16x32_bf16(wreg[cc * 2 + kc], bv[j], acc[j], 0, 0, 0);
    }
    if (cc < 7) {
      __syncthreads();
      if (cc < 6) stage(cur, (cc + 2) * 64);
      transp(cur ^ 1);
      bar_lgkm();
      cur ^= 1;
    }
  }

  #pragma unroll
  for (int j = 0; j < 4; ++j) {
    const int col = nt + j * 16 + lrow;
    #pragma unroll
    for (int r = 0; r < 4; ++r) {
      const int row = wm + quad * 4 + r;
      dst[(size_t)row * 768 + col] = f2bf(acc[j][r]);
    }
  }
}

// ---------------- bf16 GEMM, BK=64, GLDS, swizzled, XCD-chunked (R6 proven) ----------
template<int ACT, bool OF32>
__global__ __launch_bounds__(256) void gemm64_k(
    const u16* __restrict__ A, int lda,
    const u16* __restrict__ Bt, int ldb,
    void* __restrict__ Craw, int ldc,
    const u16* __restrict__ bias, int K)
{
  __shared__ u16 As[128 * 64];   // 16KB, swizzled ch^(r&7)
  __shared__ u16 Bs[128 * 64];   // 16KB, swizzled
  const int blk = blockIdx.x;                   // 768 = 128 mt x 6 nt
  const int wg = (blk & 7) * 96 + (blk >> 3);
  const int mt = (wg / 6) * 128, nt = (wg % 6) * 128;
  const int t = threadIdx.x, wave = t >> 6, lane = t & 63;
  const int wm = (wave >> 1) * 64, wn = (wave & 1) * 64;
  const int lrow = lane & 15, quad = lane >> 4;
  f32x4 acc[4][4] = {};

  for (int k0 = 0; k0 < K; k0 += 64) {
    __syncthreads();
    #pragma unroll
    for (int p = 0; p < 4; ++p) {
      const int slot = wave * 256 + p * 64 + lane;
      const int r = slot >> 3, ch = slot & 7;
      const int chs = ch ^ (r & 7);
      const int lb = (wave * 256 + p * 64) * 8;
      GLDS16(&A[(size_t)(mt + r) * lda + k0 + chs * 8], &As[lb]);
      GLDS16(&Bt[(size_t)(nt + r) * ldb + k0 + chs * 8], &Bs[lb]);
    }
    __syncthreads();

    #pragma unroll
    for (int c = 0; c < 2; ++c) {
      bf16x8 av[4], bv[4];
      #pragma unroll
      for (int i = 0; i < 4; ++i) {
        const int row = wm + i * 16 + lrow;
        av[i] = *(const bf16x8*)&As[row * 64 + (((c * 4 + quad) ^ (row & 7)) * 8)];
      }
      #pragma unroll
      for (int j = 0; j < 4; ++j) {
        const int row = wn + j * 16 + lrow;
        bv[j] = *(const bf16x8*)&Bs[row * 64 + (((c * 4 + quad) ^ (row & 7)) * 8)];
      }
      #pragma unroll
      for (int i = 0; i < 4; ++i)
        #pragma unroll
        for (int j = 0; j < 4; ++j)
          acc[i][j] = __builtin_amdgcn_mfma_f32_16x16x32_bf16(av[i], bv[j], acc[i][j], 0, 0, 0);
    }
  }

  #pragma unroll
  for (int i = 0; i < 4; ++i) {
    #pragma unroll
    for (int j = 0; j < 4; ++j) {
      const int col = nt + wn + j * 16 + lrow;
      const float badd = bias ? bf2f(bias[col]) : 0.0f;
      #pragma unroll
      for (int r = 0; r < 4; ++r) {
        const int row = mt + wm + i * 16 + quad * 4 + r;
        float v = acc[i][j][r] + badd;
        if constexpr (ACT == 1) v = v > 0.0f ? v + 1.0f : __expf(v);
        if constexpr (OF32) ((float*)Craw)[(size_t)row * ldc + col] = v;
        else                ((u16*)Craw)[(size_t)row * ldc + col] = f2bf(v);
      }
    }
  }
}

// ---------------- fused phi_k/vals GEMM + KV-state, dbuf + XCD-chunked (R16 proven) -----
__global__ __launch_bounds__(256) void fkv_k(
    const u16* __restrict__ key_ds,   // [2][32][64][768] bf16
    const u16* __restrict__ WT,       // WkT at +768^2, WvT at +2*768^2
    const u16* __restrict__ bias_c,   // bk at +768, bv at +1536
    u16* __restrict__ sT, float* __restrict__ z)
{
  __shared__ char sm[65536];
  u16* T0 = (u16*)sm;
  u16* Pt = (u16*)sm;                 // [64][72] overlay after loop
  u16* Vt = (u16*)(sm + 9216);        // [64][72]
  const int x = (blockIdx.x & 7) * 48 + (blockIdx.x >> 3);   // XCD-chunked b*12+n
  const int b = x / 12, n = x % 12;
  const int t = threadIdx.x, wave = t >> 6, lane = t & 63;
  const u16* srcs[4] = {
    key_ds + (size_t)b * 49152,
    WT + 589824 + (size_t)n * 49152,
    key_ds + 1572864 + (size_t)b * 49152,
    WT + 2 * 589824 + (size_t)n * 49152 };
  const int grow = lane >> 3;
  const int gchunk = (lane & 7) ^ (grow & 7);
  const int isV = wave & 1;
  const int wm = (wave >> 1) * 32;
  const int lrow = lane & 15, quad = lane >> 4;
  f32x4 acc[2][4] = {};

  auto stage = [&](int buf, int k0) {
    const u16* s = srcs[wave];
    char* dtile = sm + buf * 32768 + wave * 8192;
    #pragma unroll
    for (int j = 0; j < 8; ++j) {
      const u16* gsrc = s + (size_t)(j * 8 + grow) * 768 + k0 + gchunk * 8;
      GLDS16(gsrc, dtile + j * 1024);
    }
  };

  stage(0, 0);
  __syncthreads();
  int buf = 0;
  for (int ks = 0; ks < 12; ++ks) {
    if (ks < 11) stage(buf ^ 1, (ks + 1) * 64);
    const u16* Atile = T0 + buf * 16384 + (isV ? 2 : 0) * 4096;
    const u16* Btile = T0 + buf * 16384 + (isV ? 3 : 1) * 4096;
    #pragma unroll
    for (int c = 0; c < 2; ++c) {
      bf16x8 av[2], bv[4];
      #pragma unroll
      for (int i = 0; i < 2; ++i) {
        const int row = wm + i * 16 + lrow;
        av[i] = *(const bf16x8*)&Atile[row * 64 + (((c * 4 + quad) ^ (row & 7)) * 8)];
      }
      #pragma unroll
      for (int j = 0; j < 4; ++j) {
        const int row = j * 16 + lrow;
        bv[j] = *(const bf16x8*)&Btile[row * 64 + (((c * 4 + quad) ^ (row & 7)) * 8)];
      }
      #pragma unroll
      for (int i = 0; i < 2; ++i)
        #pragma unroll
        for (int j = 0; j < 4; ++j)
          acc[i][j] = __builtin_amdgcn_mfma_f32_16x16x32_bf16(av[i], bv[j], acc[i][j], 0, 0, 0);
    }
    __syncthreads();
    buf ^= 1;
  }

  const u16* bias = bias_c + (isV ? 1536 : 768) + n * 64;
  u16* Ttile = isV ? Vt : Pt;
  #pragma unroll
  for (int i = 0; i < 2; ++i)
    #pragma unroll
    for (int j = 0; j < 4; ++j) {
      const int col = j * 16 + lrow;
      const float badd = bf2f(bias[col]);
      u16x4 pk4;
      #pragma unroll
      for (int r = 0; r < 4; ++r) {
        float v = acc[i][j][r] + badd;
        if (!isV) v = v > 0.0f ? v + 1.0f : __expf(v);
        pk4[r] = f2bf(v);
      }
      *(u16x4*)&Ttile[col * 72 + wm + i * 16 + quad * 4] = pk4;
    }
  __syncthreads();

  const int wm2 = (wave >> 1) * 32, wn2 = (wave & 1) * 32;
  f32x4 a2[2][2] = {};
  #pragma unroll
  for (int c = 0; c < 2; ++c) {
    bf16x8 av[2], bv[2];
    #pragma unroll
    for (int i = 0; i < 2; ++i)
      av[i] = *(const bf16x8*)&Vt[(wm2 + i * 16 + lrow) * 72 + c * 32 + quad * 8];
    #pragma unroll
    for (int j = 0; j < 2; ++j)
      bv[j] = *(const bf16x8*)&Pt[(wn2 + j * 16 + lrow) * 72 + c * 32 + quad * 8];
    #pragma unroll
    for (int i = 0; i < 2; ++i)
      #pragma unroll
      for (int j = 0; j < 2; ++j)
        a2[i][j] = __builtin_amdgcn_mfma_f32_16x16x32_bf16(av[i], bv[j], a2[i][j], 0, 0, 0);
  }
  u16* sTg = sT + (size_t)x * 4096;
  #pragma unroll
  for (int i = 0; i < 2; ++i)
    #pragma unroll
    for (int j = 0; j < 2; ++j)
      #pragma unroll
      for (int r = 0; r < 4; ++r)
        sTg[(size_t)(wm2 + i * 16 + quad * 4 + r) * 64 + wn2 + j * 16 + lrow] = f2bf(a2[i][j][r]);
  if (t < 64) {
    float zz = 0.f;
    #pragma unroll
    for (int g = 0; g < 8; ++g) {
      u16x8 p = *(const u16x8*)&Pt[t * 72 + g * 8];
      #pragma unroll
      for (int e = 0; e < 8; ++e) zz += bf2f(p[e]);
    }
    z[(size_t)x * 64 + t] = zz;
  }
}

// ---------------- a_v = (phi_q @ s) / (phi_q . z + eps), fused qz, in-place (R6) --------
__global__ __launch_bounds__(256) void attn_av_k(
    u16* __restrict__ phi_q, const u16* __restrict__ sT, const float* __restrict__ zbuf)
{
  __shared__ u16 As[64 * 72];
  __shared__ u16 Bs[64 * 72];
  __shared__ float zv[64];
  __shared__ float zpart[4][64];
  __shared__ float zq[64];
  const int x = blockIdx.x, y = blockIdx.y;
  const int b = y / 12, n = y % 12;
  const int t = threadIdx.x;
  u16* Abase = phi_q + (size_t)b * 512 * 768 + (size_t)x * 64 * 768 + n * 64;
  const u16* Bbase = sT + (size_t)y * 4096;
  if (t < 64) zv[t] = zbuf[(size_t)y * 64 + t];
  #pragma unroll
  for (int p = 0; p < 2; ++p) {
    int v = t + p * 256;
    int r = v >> 3, c = (v & 7) * 8;
    *(u16x8*)&As[r * 72 + c] = *(const u16x8*)&Abase[(size_t)r * 768 + c];
    *(u16x8*)&Bs[r * 72 + c] = *(const u16x8*)&Bbase[r * 64 + c];
  }
  __syncthreads();
  {
    int r = t & 63, seg = t >> 6;
    float s = 0.f;
    #pragma unroll
    for (int j = 0; j < 16; ++j) s += bf2f(As[r * 72 + seg * 16 + j]) * zv[seg * 16 + j];
    zpart[seg][r] = s;
  }
  __syncthreads();
  if (t < 64) {
    float s = zpart[0][t] + zpart[1][t] + zpart[2][t] + zpart[3][t];
    zq[t] = 1.0f / (s + 1e-6f);
  }
  const int wave = t >> 6, lane = t & 63;
  const int wm = (wave >> 1) * 32, wn = (wave & 1) * 32;
  const int lrow = lane & 15, quad = lane >> 4;
  f32x4 acc[2][2] = {};
  #pragma unroll
  for (int c = 0; c < 2; ++c) {
    bf16x8 av[2], bv[2];
    #pragma unroll
    for (int i = 0; i < 2; ++i) av[i] = *(const bf16x8*)&As[(wm + i * 16 + lrow) * 72 + c * 32 + quad * 8];
    #pragma unroll
    for (int j = 0; j < 2; ++j) bv[j] = *(const bf16x8*)&Bs[(wn + j * 16 + lrow) * 72 + c * 32 + quad * 8];
    #pragma unroll
    for (int i = 0; i < 2; ++i)
      #pragma unroll
      for (int j = 0; j < 2; ++j)
        acc[i][j] = __builtin_amdgcn_mfma_f32_16x16x32_bf16(av[i], bv[j], acc[i][j], 0, 0, 0);
  }
  __syncthreads();
  #pragma unroll
  for (int i = 0; i < 2; ++i)
    #pragma unroll
    for (int j = 0; j < 2; ++j) {
      const int col = wn + j * 16 + lrow;
      #pragma unroll
      for (int r = 0; r < 4; ++r) {
        const int row = wm + i * 16 + quad * 4 + r;
        Abase[(size_t)row * 768 + col] = f2bf(acc[i][j][r] * zq[row]);
      }
    }
}

__global__ void tagfill_k(float* out, float val, int n) {
  int i = blockIdx.x * 256 + threadIdx.x;
  if (i < n) out[i] = val;
}

extern "C" void kernel_launch(void* const* d_in, const int* in_sizes, int n_in,
                              void* d_out, int out_size, void* d_ws, size_t ws_size,
                              hipStream_t stream) {
  (void)out_size;
  float* out = (float*)d_out;

  int o;
  if (n_in >= 14 && in_sizes[3] == 1) o = 4;
  else if (n_in == 13) o = 3;
  else { tagfill_k<<<4, 256, 0, stream>>>(out, 77.0f, 1024); return; }
  if (in_sizes[0] != 12582912 || in_sizes[o + 0] != 32768 || in_sizes[o + 2] != 589824) {
    tagfill_k<<<4, 256, 0, stream>>>(out, 88.0f, 1024); return;
  }

  const float* query = (const float*)d_in[0];
  const float* key   = (const float*)d_in[1];
  const float* value = (const float*)d_in[2];
  const float* W_kds = (const float*)d_in[o + 0];
  const float* W_vds = (const float*)d_in[o + 1];
  const float* Wq   = (const float*)d_in[o + 2];
  const float* bq   = (const float*)d_in[o + 3];
  const float* Wk   = (const float*)d_in[o + 4];
  const float* bk   = (const float*)d_in[o + 5];
  const float* Wv   = (const float*)d_in[o + 6];
  const float* bv   = (const float*)d_in[o + 7];
  const float* Wout = (const float*)d_in[o + 8];
  const float* bout = (const float*)d_in[o + 9];

  const size_t NEED = 61478912;
  if (ws_size < NEED) { tagfill_k<<<4, 256, 0, stream>>>(out, 123.0f, 1024); return; }

  char* base = (char*)d_ws;
  u16*   WT     = (u16*)base;                         // 4,718,592
  char*  Breg   = base + 4718592;                     // scratch region
  u16*   sT     = (u16*)Breg;                         // [384][64][64] bf16
  float* zbuf   = (float*)(Breg + 3145728);
  u16*   phi_q  = (u16*)(base + 29884416);            // 25,165,824
  u16*   bias_c = (u16*)(base + 55181312);            // 6,144
  u16*   key_ds = (u16*)(base + 55187456);            // 6,291,456
  u16* a_v = phi_q;
  u16* WqT   = WT;
  u16* WoutT = WT + 3 * 768 * 768;
  u16* bq_c = bias_c, *bout_c = bias_c + 2304;

  // 1. prep (tiny): W transposes + bias cvt
  prep_k<<<588, 256, 0, stream>>>(Wq, Wk, Wv, Wout,
                                  bq, bk, bv, bout, WT, bias_c);

  // 2. merged phi_q GEMM (query fp32 direct) + downsample
  gds_k<<<1536, 256, 0, stream>>>(query, WqT, phi_q, bq_c,
                                  W_kds, W_vds, key, value, key_ds);

  // 3. fused phi_k/vals + KV state, dbuf + XCD-chunked
  fkv_k<<<384, 256, 0, stream>>>(key_ds, WT, bias_c, sT, zbuf);

  // 4. a_v = (phi_q @ s) * 1/(phi_q.z+eps), fused qz, in-place
  attn_av_k<<<dim3(8, 384), 256, 0, stream>>>(phi_q, sT, zbuf);

  // 5. out = a_v @ Wout + bout (fp32 C, XCD-swizzled)
  gemm64_k<0, true><<<768, 256, 0, stream>>>(
      a_v, 768, WoutT, 768, out, 768, bout_c, 768);
}

// Round 19
// 282.485 us; speedup vs baseline: 1.0579x; 1.0579x over previous
//
#include <hip/hip_runtime.h>

typedef unsigned short u16;
typedef u16 u16x4 __attribute__((ext_vector_type(4)));
typedef u16 u16x8 __attribute__((ext_vector_type(8)));
typedef __bf16 bf16;
typedef bf16 bf16x8 __attribute__((ext_vector_type(8)));
typedef float f32x4 __attribute__((ext_vector_type(4)));

__device__ __forceinline__ float bf2f(u16 v) {
  union { unsigned u; float f; } x; x.u = ((unsigned)v) << 16; return x.f;
}
__device__ __forceinline__ u16 f2bf(float f) {
  union { float f; unsigned u; } x; x.f = f;
  unsigned u = x.u;
  u += 0x7fffu + ((u >> 16) & 1u);   // RNE
  return (u16)(u >> 16);
}
// hw packed f32->bf16 (RNE), 2 values / instr (no builtin on gfx950, m240)
__device__ __forceinline__ unsigned cvt2bf(float lo, float hi) {
  unsigned r;
  asm("v_cvt_pk_bf16_f32 %0, %1, %2" : "=v"(r) : "v"(lo), "v"(hi));
  return r;
}

// lgkm-only barrier: LDS drained, global loads stay in flight
__device__ __forceinline__ void bar_lgkm() {
  asm volatile("s_waitcnt lgkmcnt(0)" ::: "memory");
  __builtin_amdgcn_s_barrier();
}

// async global->LDS, 16B per lane; LDS base wave-uniform, global source per-lane (m173)
#define GLDS16(g, l) __builtin_amdgcn_global_load_lds( \
    (const __attribute__((address_space(1))) unsigned int*)(const void*)(g), \
    (__attribute__((address_space(3))) unsigned int*)(void*)(l), 16, 0, 0)

// ---------------- prep: 4 weight transposes + query cvt + bias cvts (R17 exact) ---------
// grid 6732: [0,576) transpose4; [576,6720) query fp32->bf16; [6720,6732) bias (3072)
__global__ __launch_bounds__(256) void prep_k(
    const float* __restrict__ Wq, const float* __restrict__ Wk,
    const float* __restrict__ Wv, const float* __restrict__ Wout,
    const float* __restrict__ query,
    const float* __restrict__ b0, const float* __restrict__ b1,
    const float* __restrict__ b2, const float* __restrict__ b3,
    u16* __restrict__ WT, u16* __restrict__ q_bf, u16* __restrict__ dstB)
{
  __shared__ u16 T[64][72];
  const int blk = blockIdx.x;
  const int t = threadIdx.x;
  if (blk < 576) {
    const int bz = blk / 144, rr = blk % 144;
    const int r0 = (rr / 12) * 64, c0 = (rr % 12) * 64;
    const float* W = (bz == 0) ? Wq : (bz == 1) ? Wk : (bz == 2) ? Wv : Wout;
    u16* O = WT + (size_t)bz * 768 * 768;
    #pragma unroll
    for (int p = 0; p < 2; ++p) {
      int v = t + p * 256;
      int r = v / 8, c = (v % 8) * 8;
      f32x4 x0 = *(const f32x4*)&W[(size_t)(r0 + r) * 768 + c0 + c];
      f32x4 x1 = *(const f32x4*)&W[(size_t)(r0 + r) * 768 + c0 + c + 4];
      #pragma unroll
      for (int i = 0; i < 4; ++i) { T[r][c + i] = f2bf(x0[i]); T[r][c + 4 + i] = f2bf(x1[i]); }
    }
    __syncthreads();
    #pragma unroll
    for (int p = 0; p < 2; ++p) {
      int v = t + p * 256;
      int r = v / 8, c = (v % 8) * 8;
      u16x8 tv;
      #pragma unroll
      for (int i = 0; i < 8; ++i) tv[i] = T[c + i][r];
      *(u16x8*)&O[(size_t)(c0 + r) * 768 + r0 + c] = tv;
    }
  } else if (blk < 6720) {
    const size_t i = (size_t)(blk - 576) * 256 + t;   // 6144*256 slots, *8 = 12582912
    f32x4 a = *(const f32x4*)&query[i * 8];
    f32x4 b = *(const f32x4*)&query[i * 8 + 4];
    u16x8 w;
    #pragma unroll
    for (int j = 0; j < 4; ++j) { w[j] = f2bf(a[j]); w[4 + j] = f2bf(b[j]); }
    *(u16x8*)&q_bf[i * 8] = w;
  } else {
    const int i = (blk - 6720) * 256 + t;   // 3072
    if (i < 3072) {
      int s = i / 768, si = i % 768;
      const float* src = (s == 0) ? b0 : (s == 1) ? b1 : (s == 2) ? b2 : b3;
      dstB[i] = f2bf(src[si]);
    }
  }
}

// ---------------- merged phi_q GEMM + downsample (parity-interleaved, R17 exact) --------
// Even blk: gemm64 phi_q = elu(q_bf@WqT+bq)+1 (bf16 A — R18 proved fp32-A costs +35us).
// Odd blk:  ds v8 (BW-floor-bound ~2.1 TB/s). ds reads W fp32 direct (R10 ldW).
__global__ __launch_bounds__(256) void gds_k(
    const u16* __restrict__ A,        // q_bf
    const u16* __restrict__ Bt,       // WqT
    u16* __restrict__ C,              // phi_q
    const u16* __restrict__ bias,     // bq
    const float* __restrict__ W_kds, const float* __restrict__ W_vds,
    const float* __restrict__ key, const float* __restrict__ value,
    u16* __restrict__ key_ds)
{
  __shared__ char sm[51200];
  const int t = threadIdx.x, wave = t >> 6, lane = t & 63;
  const int lrow = lane & 15, quad = lane >> 4;
  const int sub = blockIdx.x >> 1;

  if ((blockIdx.x & 1) == 0) {
    // ---- gemm64 branch ----
    u16* As = (u16*)sm;               // 16KB, swizzled ch^(r&7)
    u16* Bs = (u16*)(sm + 16384);     // 16KB
    const int wg = (sub & 7) * 96 + (sub >> 3);
    const int mt = (wg / 6) * 128, nt = (wg % 6) * 128;
    const int wm = (wave >> 1) * 64, wn = (wave & 1) * 64;
    f32x4 acc[4][4] = {};

    for (int k0 = 0; k0 < 768; k0 += 64) {
      __syncthreads();
      #pragma unroll
      for (int p = 0; p < 4; ++p) {
        const int slot = wave * 256 + p * 64 + lane;
        const int r = slot >> 3, ch = slot & 7;
        const int chs = ch ^ (r & 7);
        const int lb = (wave * 256 + p * 64) * 8;
        GLDS16(&A[(size_t)(mt + r) * 768 + k0 + chs * 8], &As[lb]);
        GLDS16(&Bt[(size_t)(nt + r) * 768 + k0 + chs * 8], &Bs[lb]);
      }
      __syncthreads();
      #pragma unroll
      for (int c = 0; c < 2; ++c) {
        bf16x8 av[4], bv[4];
        #pragma unroll
        for (int i = 0; i < 4; ++i) {
          const int row = wm + i * 16 + lrow;
          av[i] = *(const bf16x8*)&As[row * 64 + (((c * 4 + quad) ^ (row & 7)) * 8)];
        }
        #pragma unroll
        for (int j = 0; j < 4; ++j) {
          const int row = wn + j * 16 + lrow;
          bv[j] = *(const bf16x8*)&Bs[row * 64 + (((c * 4 + quad) ^ (row & 7)) * 8)];
        }
        #pragma unroll
        for (int i = 0; i < 4; ++i)
          #pragma unroll
          for (int j = 0; j < 4; ++j)
            acc[i][j] = __builtin_amdgcn_mfma_f32_16x16x32_bf16(av[i], bv[j], acc[i][j], 0, 0, 0);
      }
    }
    #pragma unroll
    for (int i = 0; i < 4; ++i)
      #pragma unroll
      for (int j = 0; j < 4; ++j) {
        const int col = nt + wn + j * 16 + lrow;
        const float badd = bf2f(bias[col]);
        #pragma unroll
        for (int r = 0; r < 4; ++r) {
          const int row = mt + wm + i * 16 + quad * 4 + r;
          float v = acc[i][j][r] + badd;
          v = v > 0.0f ? v + 1.0f : __expf(v);
          C[(size_t)row * 768 + col] = f2bf(v);
        }
      }
    return;
  }

  // ---- ds v8 branch ----
  const int id = sub;
  const int nt = (id % 12) * 64;
  const int yb = id / 12;
  const int pair = yb >> 5, b = yb & 31;
  const float* src = (pair ? value : key) + (size_t)b * 512 * 768;
  const float* W32 = pair ? W_vds : W_kds;     // fp32 [64][512], L2-hot
  u16* dst = key_ds + (size_t)pair * 1572864 + (size_t)b * 49152;
  const int wm = wave * 16;
  const int k4 = t >> 4, n4 = t & 15;

  bf16x8 wreg[16];
  #pragma unroll
  for (int c = 0; c < 16; ++c) {
    const float* wr = &W32[(size_t)(wm + lrow) * 512 + c * 32 + quad * 8];
    f32x4 w0 = *(const f32x4*)wr;
    f32x4 w1 = *(const f32x4*)(wr + 4);
    union { unsigned u[4]; bf16x8 v; } cv;
    cv.u[0] = cvt2bf(w0[0], w0[1]); cv.u[1] = cvt2bf(w0[2], w0[3]);
    cv.u[2] = cvt2bf(w1[0], w1[1]); cv.u[3] = cvt2bf(w1[2], w1[3]);
    wreg[c] = cv.v;
  }

  auto Sg = [&](int bufi) -> float* { return (float*)(sm + bufi * 16384); };
  auto Kb = [&](int bufi) -> u16*   { return (u16*)(sm + 32768 + bufi * 9216); };

  auto stage = [&](int bufi, int kb) {
    #pragma unroll
    for (int p = 0; p < 4; ++p) {
      const int g = wave * 4 + p;
      const int row = kb + g * 4 + (lane >> 4);
      const int ch = (lane & 15) ^ (g & 15);
      GLDS16(&src[(size_t)row * 768 + nt + ch * 4], (char*)Sg(bufi) + g * 1024);
    }
  };
  auto transp = [&](int bufi) {
    float* S = Sg(bufi);
    u16* K = Kb(bufi);
    f32x4 r[4];
    #pragma unroll
    for (int i = 0; i < 4; ++i) {
      const int k = k4 * 4 + i;
      r[i] = *(const f32x4*)&S[k * 64 + ((n4 ^ (k4 & 15)) & 15) * 4];
    }
    #pragma unroll
    for (int nn = 0; nn < 4; ++nn) {
      unsigned* p2 = (unsigned*)&K[(n4 * 4 + nn) * 72 + k4 * 4];
      p2[0] = cvt2bf(r[0][nn], r[1][nn]);
      p2[1] = cvt2bf(r[2][nn], r[3][nn]);
    }
  };

  f32x4 acc[4] = {};
  stage(0, 0);
  __syncthreads();
  stage(1, 64);
  transp(0);
  bar_lgkm();
  int cur = 0;
  #pragma unroll
  for (int cc = 0; cc < 8; ++cc) {
    #pragma unroll
    for (int kc = 0; kc < 2; ++kc) {
      bf16x8 bv[4];
      #pragma unroll
      for (int j = 0; j < 4; ++j) {
        const int n = j * 16 + lrow;
        bv[j] = *(const bf16x8*)&Kb(cur)[n * 72 + kc * 32 + quad * 8];
      }
      #pragma unroll
      for (int j = 0; j < 4; ++j)
        acc[j] = __builtin_amdgcn_mfma_f32_16x16x32_bf16(wreg[cc * 2 + kc], bv[j], acc[j], 0, 0, 0);
    }
    if (cc < 7) {
      __syncthreads();
      if (cc < 6) stage(cur, (cc + 2) * 64);
      transp(cur ^ 1);
      bar_lgkm();
      cur ^= 1;
    }
  }

  #pragma unroll
  for (int j = 0; j < 4; ++j) {
    const int col = nt + j * 16 + lrow;
    #pragma unroll
    for (int r = 0; r < 4; ++r) {
      const int row = wm + quad * 4 + r;
      dst[(size_t)row * 768 + col] = f2bf(acc[j][r]);
    }
  }
}

// ---------------- bf16 GEMM, BK=64, GLDS, swizzled, XCD-chunked (R6 proven) ----------
template<int ACT, bool OF32>
__global__ __launch_bounds__(256) void gemm64_k(
    const u16* __restrict__ A, int lda,
    const u16* __restrict__ Bt, int ldb,
    void* __restrict__ Craw, int ldc,
    const u16* __restrict__ bias, int K)
{
  __shared__ u16 As[128 * 64];   // 16KB, swizzled ch^(r&7)
  __shared__ u16 Bs[128 * 64];   // 16KB, swizzled
  const int blk = blockIdx.x;                   // 768 = 128 mt x 6 nt
  const int wg = (blk & 7) * 96 + (blk >> 3);
  const int mt = (wg / 6) * 128, nt = (wg % 6) * 128;
  const int t = threadIdx.x, wave = t >> 6, lane = t & 63;
  const int wm = (wave >> 1) * 64, wn = (wave & 1) * 64;
  const int lrow = lane & 15, quad = lane >> 4;
  f32x4 acc[4][4] = {};

  for (int k0 = 0; k0 < K; k0 += 64) {
    __syncthreads();
    #pragma unroll
    for (int p = 0; p < 4; ++p) {
      const int slot = wave * 256 + p * 64 + lane;
      const int r = slot >> 3, ch = slot & 7;
      const int chs = ch ^ (r & 7);
      const int lb = (wave * 256 + p * 64) * 8;
      GLDS16(&A[(size_t)(mt + r) * lda + k0 + chs * 8], &As[lb]);
      GLDS16(&Bt[(size_t)(nt + r) * ldb + k0 + chs * 8], &Bs[lb]);
    }
    __syncthreads();

    #pragma unroll
    for (int c = 0; c < 2; ++c) {
      bf16x8 av[4], bv[4];
      #pragma unroll
      for (int i = 0; i < 4; ++i) {
        const int row = wm + i * 16 + lrow;
        av[i] = *(const bf16x8*)&As[row * 64 + (((c * 4 + quad) ^ (row & 7)) * 8)];
      }
      #pragma unroll
      for (int j = 0; j < 4; ++j) {
        const int row = wn + j * 16 + lrow;
        bv[j] = *(const bf16x8*)&Bs[row * 64 + (((c * 4 + quad) ^ (row & 7)) * 8)];
      }
      #pragma unroll
      for (int i = 0; i < 4; ++i)
        #pragma unroll
        for (int j = 0; j < 4; ++j)
          acc[i][j] = __builtin_amdgcn_mfma_f32_16x16x32_bf16(av[i], bv[j], acc[i][j], 0, 0, 0);
    }
  }

  #pragma unroll
  for (int i = 0; i < 4; ++i) {
    #pragma unroll
    for (int j = 0; j < 4; ++j) {
      const int col = nt + wn + j * 16 + lrow;
      const float badd = bias ? bf2f(bias[col]) : 0.0f;
      #pragma unroll
      for (int r = 0; r < 4; ++r) {
        const int row = mt + wm + i * 16 + quad * 4 + r;
        float v = acc[i][j][r] + badd;
        if constexpr (ACT == 1) v = v > 0.0f ? v + 1.0f : __expf(v);
        if constexpr (OF32) ((float*)Craw)[(size_t)row * ldc + col] = v;
        else                ((u16*)Craw)[(size_t)row * ldc + col] = f2bf(v);
      }
    }
  }
}

// ---------------- fused phi_k/vals GEMM + KV-state, dbuf + XCD-chunked (R16 proven) -----
__global__ __launch_bounds__(256) void fkv_k(
    const u16* __restrict__ key_ds,   // [2][32][64][768] bf16
    const u16* __restrict__ WT,       // WkT at +768^2, WvT at +2*768^2
    const u16* __restrict__ bias_c,   // bk at +768, bv at +1536
    u16* __restrict__ sT, float* __restrict__ z)
{
  __shared__ char sm[65536];
  u16* T0 = (u16*)sm;
  u16* Pt = (u16*)sm;                 // [64][72] overlay after loop
  u16* Vt = (u16*)(sm + 9216);        // [64][72]
  const int x = (blockIdx.x & 7) * 48 + (blockIdx.x >> 3);   // XCD-chunked b*12+n
  const int b = x / 12, n = x % 12;
  const int t = threadIdx.x, wave = t >> 6, lane = t & 63;
  const u16* srcs[4] = {
    key_ds + (size_t)b * 49152,
    WT + 589824 + (size_t)n * 49152,
    key_ds + 1572864 + (size_t)b * 49152,
    WT + 2 * 589824 + (size_t)n * 49152 };
  const int grow = lane >> 3;
  const int gchunk = (lane & 7) ^ (grow & 7);
  const int isV = wave & 1;
  const int wm = (wave >> 1) * 32;
  const int lrow = lane & 15, quad = lane >> 4;
  f32x4 acc[2][4] = {};

  auto stage = [&](int buf, int k0) {
    const u16* s = srcs[wave];
    char* dtile = sm + buf * 32768 + wave * 8192;
    #pragma unroll
    for (int j = 0; j < 8; ++j) {
      const u16* gsrc = s + (size_t)(j * 8 + grow) * 768 + k0 + gchunk * 8;
      GLDS16(gsrc, dtile + j * 1024);
    }
  };

  stage(0, 0);
  __syncthreads();
  int buf = 0;
  for (int ks = 0; ks < 12; ++ks) {
    if (ks < 11) stage(buf ^ 1, (ks + 1) * 64);
    const u16* Atile = T0 + buf * 16384 + (isV ? 2 : 0) * 4096;
    const u16* Btile = T0 + buf * 16384 + (isV ? 3 : 1) * 4096;
    #pragma unroll
    for (int c = 0; c < 2; ++c) {
      bf16x8 av[2], bv[4];
      #pragma unroll
      for (int i = 0; i < 2; ++i) {
        const int row = wm + i * 16 + lrow;
        av[i] = *(const bf16x8*)&Atile[row * 64 + (((c * 4 + quad) ^ (row & 7)) * 8)];
      }
      #pragma unroll
      for (int j = 0; j < 4; ++j) {
        const int row = j * 16 + lrow;
        bv[j] = *(const bf16x8*)&Btile[row * 64 + (((c * 4 + quad) ^ (row & 7)) * 8)];
      }
      #pragma unroll
      for (int i = 0; i < 2; ++i)
        #pragma unroll
        for (int j = 0; j < 4; ++j)
          acc[i][j] = __builtin_amdgcn_mfma_f32_16x16x32_bf16(av[i], bv[j], acc[i][j], 0, 0, 0);
    }
    __syncthreads();
    buf ^= 1;
  }

  const u16* bias = bias_c + (isV ? 1536 : 768) + n * 64;
  u16* Ttile = isV ? Vt : Pt;
  #pragma unroll
  for (int i = 0; i < 2; ++i)
    #pragma unroll
    for (int j = 0; j < 4; ++j) {
      const int col = j * 16 + lrow;
      const float badd = bf2f(bias[col]);
      u16x4 pk4;
      #pragma unroll
      for (int r = 0; r < 4; ++r) {
        float v = acc[i][j][r] + badd;
        if (!isV) v = v > 0.0f ? v + 1.0f : __expf(v);
        pk4[r] = f2bf(v);
      }
      *(u16x4*)&Ttile[col * 72 + wm + i * 16 + quad * 4] = pk4;
    }
  __syncthreads();

  const int wm2 = (wave >> 1) * 32, wn2 = (wave & 1) * 32;
  f32x4 a2[2][2] = {};
  #pragma unroll
  for (int c = 0; c < 2; ++c) {
    bf16x8 av[2], bv[2];
    #pragma unroll
    for (int i = 0; i < 2; ++i)
      av[i] = *(const bf16x8*)&Vt[(wm2 + i * 16 + lrow) * 72 + c * 32 + quad * 8];
    #pragma unroll
    for (int j = 0; j < 2; ++j)
      bv[j] = *(const bf16x8*)&Pt[(wn2 + j * 16 + lrow) * 72 + c * 32 + quad * 8];
    #pragma unroll
    for (int i = 0; i < 2; ++i)
      #pragma unroll
      for (int j = 0; j < 2; ++j)
        a2[i][j] = __builtin_amdgcn_mfma_f32_16x16x32_bf16(av[i], bv[j], a2[i][j], 0, 0, 0);
  }
  u16* sTg = sT + (size_t)x * 4096;
  #pragma unroll
  for (int i = 0; i < 2; ++i)
    #pragma unroll
    for (int j = 0; j < 2; ++j)
      #pragma unroll
      for (int r = 0; r < 4; ++r)
        sTg[(size_t)(wm2 + i * 16 + quad * 4 + r) * 64 + wn2 + j * 16 + lrow] = f2bf(a2[i][j][r]);
  if (t < 64) {
    float zz = 0.f;
    #pragma unroll
    for (int g = 0; g < 8; ++g) {
      u16x8 p = *(const u16x8*)&Pt[t * 72 + g * 8];
      #pragma unroll
      for (int e = 0; e < 8; ++e) zz += bf2f(p[e]);
    }
    z[(size_t)x * 64 + t] = zz;
  }
}

// ---------------- a_v = (phi_q @ s) / (phi_q . z + eps), fused qz, in-place (R6) --------
__global__ __launch_bounds__(256) void attn_av_k(
    u16* __restrict__ phi_q, const u16* __restrict__ sT, const float* __restrict__ zbuf)
{
  __shared__ u16 As[64 * 72];
  __shared__ u16 Bs[64 * 72];
  __shared__ float zv[64];
  __shared__ float zpart[4][64];
  __shared__ float zq[64];
  const int x = blockIdx.x, y = blockIdx.y;
  const int b = y / 12, n = y % 12;
  const int t = threadIdx.x;
  u16* Abase = phi_q + (size_t)b * 512 * 768 + (size_t)x * 64 * 768 + n * 64;
  const u16* Bbase = sT + (size_t)y * 4096;
  if (t < 64) zv[t] = zbuf[(size_t)y * 64 + t];
  #pragma unroll
  for (int p = 0; p < 2; ++p) {
    int v = t + p * 256;
    int r = v >> 3, c = (v & 7) * 8;
    *(u16x8*)&As[r * 72 + c] = *(const u16x8*)&Abase[(size_t)r * 768 + c];
    *(u16x8*)&Bs[r * 72 + c] = *(const u16x8*)&Bbase[r * 64 + c];
  }
  __syncthreads();
  {
    int r = t & 63, seg = t >> 6;
    float s = 0.f;
    #pragma unroll
    for (int j = 0; j < 16; ++j) s += bf2f(As[r * 72 + seg * 16 + j]) * zv[seg * 16 + j];
    zpart[seg][r] = s;
  }
  __syncthreads();
  if (t < 64) {
    float s = zpart[0][t] + zpart[1][t] + zpart[2][t] + zpart[3][t];
    zq[t] = 1.0f / (s + 1e-6f);
  }
  const int wave = t >> 6, lane = t & 63;
  const int wm = (wave >> 1) * 32, wn = (wave & 1) * 32;
  const int lrow = lane & 15, quad = lane >> 4;
  f32x4 acc[2][2] = {};
  #pragma unroll
  for (int c = 0; c < 2; ++c) {
    bf16x8 av[2], bv[2];
    #pragma unroll
    for (int i = 0; i < 2; ++i) av[i] = *(const bf16x8*)&As[(wm + i * 16 + lrow) * 72 + c * 32 + quad * 8];
    #pragma unroll
    for (int j = 0; j < 2; ++j) bv[j] = *(const bf16x8*)&Bs[(wn + j * 16 + lrow) * 72 + c * 32 + quad * 8];
    #pragma unroll
    for (int i = 0; i < 2; ++i)
      #pragma unroll
      for (int j = 0; j < 2; ++j)
        acc[i][j] = __builtin_amdgcn_mfma_f32_16x16x32_bf16(av[i], bv[j], acc[i][j], 0, 0, 0);
  }
  __syncthreads();
  #pragma unroll
  for (int i = 0; i < 2; ++i)
    #pragma unroll
    for (int j = 0; j < 2; ++j) {
      const int col = wn + j * 16 + lrow;
      #pragma unroll
      for (int r = 0; r < 4; ++r) {
        const int row = wm + i * 16 + quad * 4 + r;
        Abase[(size_t)row * 768 + col] = f2bf(acc[i][j][r] * zq[row]);
      }
    }
}

__global__ void tagfill_k(float* out, float val, int n) {
  int i = blockIdx.x * 256 + threadIdx.x;
  if (i < n) out[i] = val;
}

extern "C" void kernel_launch(void* const* d_in, const int* in_sizes, int n_in,
                              void* d_out, int out_size, void* d_ws, size_t ws_size,
                              hipStream_t stream) {
  (void)out_size;
  float* out = (float*)d_out;

  int o;
  if (n_in >= 14 && in_sizes[3] == 1) o = 4;
  else if (n_in == 13) o = 3;
  else { tagfill_k<<<4, 256, 0, stream>>>(out, 77.0f, 1024); return; }
  if (in_sizes[0] != 12582912 || in_sizes[o + 0] != 32768 || in_sizes[o + 2] != 589824) {
    tagfill_k<<<4, 256, 0, stream>>>(out, 88.0f, 1024); return;
  }

  const float* query = (const float*)d_in[0];
  const float* key   = (const float*)d_in[1];
  const float* value = (const float*)d_in[2];
  const float* W_kds = (const float*)d_in[o + 0];
  const float* W_vds = (const float*)d_in[o + 1];
  const float* Wq   = (const float*)d_in[o + 2];
  const float* bq   = (const float*)d_in[o + 3];
  const float* Wk   = (const float*)d_in[o + 4];
  const float* bk   = (const float*)d_in[o + 5];
  const float* Wv   = (const float*)d_in[o + 6];
  const float* bv   = (const float*)d_in[o + 7];
  const float* Wout = (const float*)d_in[o + 8];
  const float* bout = (const float*)d_in[o + 9];

  const size_t NEED = 61478912;
  if (ws_size < NEED) { tagfill_k<<<4, 256, 0, stream>>>(out, 123.0f, 1024); return; }

  char* base = (char*)d_ws;
  u16*   WT     = (u16*)base;                         // 4,718,592
  char*  Breg   = base + 4718592;                     // 25,165,824 region
  u16*   q_bf   = (u16*)Breg;                         // dies after gds (phi_q GEMM)
  u16*   sT     = (u16*)Breg;                         // then sT (over dead q_bf)
  float* zbuf   = (float*)(Breg + 3145728);
  u16*   phi_q  = (u16*)(base + 29884416);            // 25,165,824
  u16*   bias_c = (u16*)(base + 55181312);            // 6,144
  u16*   key_ds = (u16*)(base + 55187456);            // 6,291,456
  u16* a_v = phi_q;
  u16* WqT   = WT;
  u16* WoutT = WT + 3 * 768 * 768;
  u16* bq_c = bias_c, *bout_c = bias_c + 2304;

  // 1. prep: W transposes + query cvt + bias cvt
  prep_k<<<6732, 256, 0, stream>>>(Wq, Wk, Wv, Wout, query,
                                   bq, bk, bv, bout, WT, q_bf, bias_c);

  // 2. merged phi_q GEMM + downsample (parity-interleaved; ds reads W fp32 direct)
  gds_k<<<1536, 256, 0, stream>>>(q_bf, WqT, phi_q, bq_c,
                                  W_kds, W_vds, key, value, key_ds);

  // 3. fused phi_k/vals + KV state, dbuf + XCD-chunked (sT/zbuf overwrite dead q_bf)
  fkv_k<<<384, 256, 0, stream>>>(key_ds, WT, bias_c, sT, zbuf);

  // 4. a_v = (phi_q @ s) * 1/(phi_q.z+eps), fused qz, in-place
  attn_av_k<<<dim3(8, 384), 256, 0, stream>>>(phi_q, sT, zbuf);

  // 5. out = a_v @ Wout + bout (fp32 C, XCD-swizzled)
  gemm64_k<0, true><<<768, 256, 0, stream>>>(
      a_v, 768, WoutT, 768, out, 768, bout_c, 768);
}